// Round 1
// baseline (23994.000 us; speedup 1.0000x reference)
//
#include <hip/hip_runtime.h>
#include <hip/hip_bf16.h>

// B=64, T=512, D=H=1024, 2-layer masked LSTM. Persistent kernel, 128 WGs x 512 thr.
// v4: (a) flattened epoch barriers: producers bump their leaf, consumers poll all
//     8 leaves concurrently (1 L3 RTT instead of leaf->root->bcast = 3 hops);
// (b) WG pairs merged into 512-thread WGs (two independent 4-wave column-halves)
//     -> 64 global communicators per layer instead of 128 (fan-in, skew, poll
//     churn and coherent-read fetch count halved); VGPR 216 => 2 waves/SIMD ok;
// (c) rnnout f32 stores deferred until after the arrive-add so the per-step
//     s_waitcnt vmcnt(0) only drains the coherent h-ring stores.
// h state still flows through agent-scope (sc0/sc1, L2-bypassing) atomic
// loads/stores; x + weights stay L2/VGPR-resident. Layer0 free-runs up to 3
// steps ahead (h0 ring of 4); layer1 waits on epoch0 >= t+1.

#define NTT 512

typedef __attribute__((ext_vector_type(8))) short short8;
typedef __attribute__((ext_vector_type(4))) float floatx4;
typedef __attribute__((ext_vector_type(4))) unsigned short ushort4v;
typedef unsigned long long ull;

#define LDS_TOTAL 90112  // force 1 WG/CU; first 2x24KB = per-half reduction bufs

#define AT_LD(p) __hip_atomic_load((p), __ATOMIC_RELAXED, __HIP_MEMORY_SCOPE_AGENT)
#define AT_ST(p, v) __hip_atomic_store((p), (v), __ATOMIC_RELAXED, __HIP_MEMORY_SCOPE_AGENT)
#define AT_ADD(p, v) __hip_atomic_fetch_add((p), (v), __ATOMIC_RELAXED, __HIP_MEMORY_SCOPE_AGENT)

__device__ __forceinline__ unsigned short f2bf(float f) {
  unsigned int u = __float_as_uint(f);
  u += 0x7fffu + ((u >> 16) & 1u);  // RNE
  return (unsigned short)(u >> 16);
}
__device__ __forceinline__ float sigmf(float x) { return 1.0f / (1.0f + __expf(-x)); }
__device__ __forceinline__ float tanhfa(float x) { return 1.0f - 2.0f / (1.0f + __expf(2.0f * x)); }

// ---- phase-0 flat full-grid barrier (128 WGs), WITH full fences
// (publishes xz staging + hbuf zeros via L2 writeback / invalidate)
__device__ __forceinline__ void fullbar(ull* fb) {
  __syncthreads();
  if (threadIdx.x == 0) {
    __builtin_amdgcn_fence(__ATOMIC_RELEASE, "agent");
    AT_ADD(fb, 1ull);
    while (AT_LD(fb) < 128ull) __builtin_amdgcn_s_sleep(1);
    __builtin_amdgcn_fence(__ATOMIC_ACQUIRE, "agent");
  }
  __syncthreads();
}

// ---- flattened per-layer epoch barrier ----
// arrive: +1 on this WG's leaf, after all 8 waves' h sc-stores acked at L3
__device__ __forceinline__ void layer_arrive(ull* base, int sub64) {
  asm volatile("s_waitcnt vmcnt(0)" ::: "memory");  // per-wave: h stores at L3
  __syncthreads();
  if (threadIdx.x == 0) AT_ADD(base + 16 + 16 * (sub64 & 7), 1ull);
}

// min over the 8 leaf counters; 8 independent loads -> ~one L3 RTT per round
__device__ __forceinline__ ull leafmin(const ull* base) {
  ull v[8];
#pragma unroll
  for (int l = 0; l < 8; ++l) v[l] = AT_LD(base + 16 + 16 * l);
  ull m = v[0];
#pragma unroll
  for (int l = 1; l < 8; ++l) m = v[l] < m ? v[l] : m;
  return m;
}

// wait: all leaves of own >= 8*ot and of oth >= 8*xt (skip if <=0)
__device__ __forceinline__ void wait2(const ull* own, long long ot, const ull* oth, long long xt) {
  if (threadIdx.x == 0) {
    if (ot > 0) {
      const ull tgt = 8ull * (ull)ot;
      while (leafmin(own) < tgt) __builtin_amdgcn_s_sleep(1);
    }
    if (xt > 0) {
      const ull tgt = 8ull * (ull)xt;
      while (leafmin(oth) < tgt) __builtin_amdgcn_s_sleep(1);
    }
  }
  __syncthreads();
}

// ---- A-fragment load: COH = agent-coherent (L2-bypass) path for h buffers
template <bool COH>
__device__ __forceinline__ short8 ldfrag(const char* p) {
  if constexpr (COH) {
    union { short8 s; ull q[2]; } u;
    u.q[0] = AT_LD((const ull*)p);
    u.q[1] = AT_LD((const ull*)(p + 8));
    return u.s;
  } else {
    return *(const short8*)p;
  }
}

template <bool COH>
__device__ __forceinline__ void ringfill(const char* const* aPm, short8 (*af)[4]) {
#pragma unroll
  for (int kt = 0; kt < 8; ++kt)
#pragma unroll
    for (int mt = 0; mt < 4; ++mt) af[kt][mt] = ldfrag<COH>(aPm[mt] + kt * 64);
}

template <bool COH>
__device__ __forceinline__ void kmain(const char* const* aPm, short8 (*af)[4],
                                      const short8 (*bfr)[2], floatx4 (*acc)[2]) {
#pragma unroll
  for (int kt = 0; kt < 16; ++kt) {
#pragma unroll
    for (int mt = 0; mt < 4; ++mt)
#pragma unroll
      for (int nt = 0; nt < 2; ++nt)
        acc[mt][nt] = __builtin_amdgcn_mfma_f32_16x16x32_bf16(
            af[kt & 7][mt], bfr[kt][nt], acc[mt][nt], 0, 0, 0);
    if (kt < 8) {
#pragma unroll
      for (int mt = 0; mt < 4; ++mt)
        af[kt & 7][mt] = ldfrag<COH>(aPm[mt] + (kt + 8) * 64);
    }
  }
}

__global__ __launch_bounds__(512, 2) void lstm2_persist(
    const float* __restrict__ xin, const int* __restrict__ lens,
    const float* __restrict__ W0, const float* __restrict__ U0, const float* __restrict__ b0v,
    const float* __restrict__ W1, const float* __restrict__ U1, const float* __restrict__ b1v,
    float* __restrict__ out, ull* __restrict__ ws) {
  extern __shared__ char smem[];

  ull* bar0 = ws;           // layer-0 epoch leaves @16+16l (128B apart)
  ull* bar1 = ws + 512;     // layer-1 epoch leaves
  ull* fbar = ws + 1024;    // phase-0 flat full barrier
  unsigned short* hbufs = (unsigned short*)(ws + 2048);  // byte 16384

  const int tid = threadIdx.x;
  const int bid = blockIdx.x;
  const int half = tid >> 8;              // which 4-wave column-half of this WG
  float* red = (float*)(smem + half * 24576);  // per-half [12][2][64][4] f32

  const int layer = bid >> 6;
  const int sub64 = bid & 63;             // communicator id within layer
  const int sub = sub64 * 2 + half;       // 0..127 column-slice id (8 h-cols)
  const int hc0 = sub * 8;
  const int wave = (tid >> 6) & 3;        // wave within the half
  const int lane = tid & 63;
  const int c16 = lane & 15;
  const int rowgrp = lane >> 4;

  // h0 ring of 4 (layer0 may run ahead), h1 ping-pong of 2. 64x1024 bf16 each.
  unsigned short* h0r[4] = {hbufs, hbufs + 65536, hbufs + 131072, hbufs + 196608};
  unsigned short* h1r[2] = {hbufs + 262144, hbufs + 327680};

  // ---------------- phase 0 ----------------
  const unsigned int gid = (unsigned int)bid * 512u + (unsigned int)tid;
  for (unsigned int i = gid; i < 196608u; i += 65536u) ((unsigned int*)hbufs)[i] = 0u;
  {
    // x (B,T,D) fp32 -> bf16 aliased into d_out at (b*512+t)*4096 bytes.
    const floatx4* xs = (const floatx4*)xin;
    for (unsigned int q = gid; q < 8388608u; q += 65536u) {
      unsigned int d4 = q & 255u;
      unsigned int bt = q >> 8;
      floatx4 v = xs[q];
      ushort4v o;
      o.x = f2bf(v.x); o.y = f2bf(v.y); o.z = f2bf(v.z); o.w = f2bf(v.w);
      *((ushort4v*)((char*)out + (size_t)bt * 4096) + d4) = o;
    }
  }
  // B fragments -> VGPRs (per half: wave w<2 = W rows, w>=2 = U rows)
  const float* Wm = layer ? W1 : W0;
  const float* Um = layer ? U1 : U0;
  const float* Bsrc = (wave < 2) ? Wm : Um;
  const int kbase = (wave & 1) * 512;
  short8 bf[16][2];
#pragma unroll
  for (int kt = 0; kt < 16; ++kt)
#pragma unroll
    for (int nt = 0; nt < 2; ++nt) {
      const int zc = (nt * 2 + (c16 >> 3)) * 1024 + hc0 + (c16 & 7);
      const float* col = Bsrc + (size_t)(kbase + kt * 32 + rowgrp * 8) * 4096 + zc;
      short8 v;
#pragma unroll
      for (int j = 0; j < 8; ++j) v[j] = (short)f2bf(col[(size_t)j * 4096]);
      bf[kt][nt] = v;
    }
  const float* bv = layer ? b1v : b0v;
  const float bias0 = bv[(c16 >> 3) * 1024 + hc0 + (c16 & 7)];
  const float bias1 = bv[(2 + (c16 >> 3)) * 1024 + hc0 + (c16 & 7)];
  int lens4[4];
#pragma unroll
  for (int r = 0; r < 4; ++r) lens4[r] = lens[wave * 16 + rowgrp * 4 + r];

  fullbar(fbar);

  // ---------------- recurrence ----------------
  float hst[4] = {0.f, 0.f, 0.f, 0.f};
  float cst[4] = {0.f, 0.f, 0.f, 0.f};
  const int col = hc0 + c16;

#pragma unroll 1
  for (int t = 0; t < NTT; ++t) {
    const char* aPm[4];
    short8 af[8][4];
    bool isX;  // this wave's A comes from x (normal loads) vs h (coherent loads)
    {
      const char* base0;
      size_t pitch;
      if (layer == 0) {
        if (wave < 2) { base0 = (const char*)out + (size_t)t * 4096 + (size_t)wave * 1024;
                        pitch = (size_t)NTT * 4096; isX = true; }
        else          { base0 = (const char*)h0r[(t + 3) & 3] + (size_t)(wave - 2) * 1024;
                        pitch = 2048; isX = false; }
      } else {
        if (wave < 2) { base0 = (const char*)h0r[t & 3] + (size_t)wave * 1024; }
        else          { base0 = (const char*)h1r[(t + 1) & 1] + (size_t)(wave - 2) * 1024; }
        pitch = 2048; isX = false;
      }
      const char* aP = base0 + (size_t)c16 * pitch + (size_t)rowgrp * 16;
#pragma unroll
      for (int mt = 0; mt < 4; ++mt) aPm[mt] = aP + (size_t)mt * 16 * pitch;
    }

    if (isX) ringfill<false>(aPm, af);  // x is static: prefetch before the wait

    if (layer == 0) wait2(bar0, t, bar1, (long long)t - 3);
    else            wait2(bar1, t, bar0, (long long)t + 1);

    floatx4 acc[4][2];
#pragma unroll
    for (int mt = 0; mt < 4; ++mt)
#pragma unroll
      for (int nt = 0; nt < 2; ++nt) { floatx4 z = {0.f, 0.f, 0.f, 0.f}; acc[mt][nt] = z; }

    if (isX) {
      kmain<false>(aPm, af, bf, acc);
    } else {
      ringfill<true>(aPm, af);
      kmain<true>(aPm, af, bf, acc);
    }

    // cross-wave K reduction within the half (wave keeps m-tile == wave)
#pragma unroll
    for (int mt = 0; mt < 4; ++mt)
      if (mt != wave) {
        int slot = mt * 3 + wave - (wave > mt ? 1 : 0);
        *(floatx4*)&red[((slot * 2 + 0) * 64 + lane) * 4] = acc[mt][0];
        *(floatx4*)&red[((slot * 2 + 1) * 64 + lane) * 4] = acc[mt][1];
      }
    __syncthreads();
    floatx4 z0 = acc[wave][0], z1 = acc[wave][1];
#pragma unroll
    for (int q = 0; q < 3; ++q) {
      int slot = wave * 3 + q;
      z0 += *(const floatx4*)&red[((slot * 2 + 0) * 64 + lane) * 4];
      z1 += *(const floatx4*)&red[((slot * 2 + 1) * 64 + lane) * 4];
    }
    z0 += bias0;
    z1 += bias1;

    unsigned short* hW = layer ? h1r[t & 1] : h0r[t & 3];
    float2 f2s[4];

#pragma unroll
    for (int r = 0; r < 4; ++r) {
      float zi = z0[r], zg = z1[r];
      float zf = __shfl_xor(zi, 8);
      float zo = __shfl_xor(zg, 8);
      float h2, hu_f = 0.f;
      unsigned short hu = 0;
      if (c16 < 8) {
        float ig = sigmf(zi), fg = sigmf(zf), gg = tanhfa(zg), og = sigmf(zo);
        float cn = fg * cst[r] + ig * gg;
        float hn = og * tanhfa(cn);
        bool m = t < lens4[r];
        h2 = m ? hn : hst[r];
        float c2 = m ? cn : cst[r];
        hst[r] = h2;
        cst[r] = c2;
        hu = f2bf(h2);
        hu_f = h2;
      }
      // pair adjacent cols -> one u32 coherent store
      unsigned int up = __shfl_xor((unsigned int)hu, 1);
      float hp = __shfl_xor(hu_f, 1);
      if (c16 < 8 && !(c16 & 1)) {
        int b = wave * 16 + rowgrp * 4 + r;
        unsigned int w = (unsigned int)hu | (up << 16);
        AT_ST((unsigned int*)(hW + b * 1024 + col), w);
        f2s[r] = make_float2(hu_f, hp);
      }
    }

    if (layer == 0) layer_arrive(bar0, sub64);
    else            layer_arrive(bar1, sub64);

    // rnnout f32 stores AFTER the arrive: off the vmcnt(0) drain path;
    // they complete during the next step's wait.
    if (layer && c16 < 8 && !(c16 & 1)) {
#pragma unroll
      for (int r = 0; r < 4; ++r) {
        int b = wave * 16 + rowgrp * 4 + r;
        *(float2*)&out[((size_t)b * 512 + (size_t)t) * 1024 + col] = f2s[r];
      }
    }
  }

  if (layer && c16 < 8) {
#pragma unroll
    for (int r = 0; r < 4; ++r) {
      int b = wave * 16 + rowgrp * 4 + r;
      out[(size_t)33554432 + (size_t)b * 1024 + col] = hst[r];
      out[(size_t)33554432 + 65536 + (size_t)b * 1024 + col] = cst[r];
    }
  }
}

extern "C" void kernel_launch(void* const* d_in, const int* in_sizes, int n_in,
                              void* d_out, int out_size, void* d_ws, size_t ws_size,
                              hipStream_t stream) {
  (void)in_sizes; (void)n_in; (void)out_size; (void)ws_size;
  const float* x  = (const float*)d_in[0];
  const int* lens = (const int*)d_in[1];
  const float* W0 = (const float*)d_in[2];
  const float* U0 = (const float*)d_in[3];
  const float* b0 = (const float*)d_in[4];
  const float* W1 = (const float*)d_in[5];
  const float* U1 = (const float*)d_in[6];
  const float* b1 = (const float*)d_in[7];

  (void)hipFuncSetAttribute((const void*)lstm2_persist,
                            hipFuncAttributeMaxDynamicSharedMemorySize, LDS_TOTAL);
  hipMemsetAsync(d_ws, 0, 16384, stream);  // bar0/bar1/fbar

  lstm2_persist<<<dim3(128), dim3(512), LDS_TOTAL, stream>>>(
      x, lens, W0, U0, b0, W1, U1, b1, (float*)d_out, (ull*)d_ws);
}

// Round 2
// 9748.056 us; speedup vs baseline: 2.4614x; 2.4614x over previous
//
#include <hip/hip_runtime.h>
#include <hip/hip_bf16.h>

// B=64, T=512, D=H=1024, 2-layer masked LSTM. Persistent kernel, 256 WGs x 256 thr.
// v5 (back to v3's 256x256 register-safe shape; v4's 512-thr merge spilled weights):
// (a) h-consumer loads are now NORMAL CACHED dwordx4 loads (L2-served, shared
//     per-XCD) instead of 8B L2-bypassing atomic loads; coherence restored by a
//     per-step agent-ACQUIRE fence (buffer_inv: clean-line invalidate; h lines are
//     never dirty in L2 since producers store via sc-bypass, so inv-only is sound).
//     Producers unchanged: sc-stores -> vmcnt(0) -> leaf add (release by drain).
// (b) flattened epoch barriers: producers bump their leaf; consumers poll all 8
//     leaves concurrently (1 L3 RTT) for >= 16*t instead of leaf->root->bcast.
// (c) rnnout f32 stores deferred until after the arrive-add (off the vmcnt(0)
//     drain path; they complete during the next step's wait).
// Layer0 free-runs up to 3 steps ahead (h0 ring of 4); layer1 waits epoch0 >= t+1.

#define NTT 512

typedef __attribute__((ext_vector_type(8))) short short8;
typedef __attribute__((ext_vector_type(4))) float floatx4;
typedef __attribute__((ext_vector_type(4))) unsigned short ushort4v;
typedef unsigned long long ull;

#define LDS_TOTAL 90112  // force 1 WG/CU; first 24KB = reduction buf

#define AT_LD(p) __hip_atomic_load((p), __ATOMIC_RELAXED, __HIP_MEMORY_SCOPE_AGENT)
#define AT_ST(p, v) __hip_atomic_store((p), (v), __ATOMIC_RELAXED, __HIP_MEMORY_SCOPE_AGENT)
#define AT_ADD(p, v) __hip_atomic_fetch_add((p), (v), __ATOMIC_RELAXED, __HIP_MEMORY_SCOPE_AGENT)

__device__ __forceinline__ unsigned short f2bf(float f) {
  unsigned int u = __float_as_uint(f);
  u += 0x7fffu + ((u >> 16) & 1u);  // RNE
  return (unsigned short)(u >> 16);
}
__device__ __forceinline__ float sigmf(float x) { return 1.0f / (1.0f + __expf(-x)); }
__device__ __forceinline__ float tanhfa(float x) { return 1.0f - 2.0f / (1.0f + __expf(2.0f * x)); }

// ---- phase-0 flat full-grid barrier (256 WGs), WITH full fences
// (release publishes xz staging + hbuf zeros; acquire invalidates stale L2)
__device__ __forceinline__ void fullbar(ull* fb) {
  __syncthreads();
  if (threadIdx.x == 0) {
    __builtin_amdgcn_fence(__ATOMIC_RELEASE, "agent");
    AT_ADD(fb, 1ull);
    while (AT_LD(fb) < 256ull) __builtin_amdgcn_s_sleep(1);
    __builtin_amdgcn_fence(__ATOMIC_ACQUIRE, "agent");
  }
  __syncthreads();
}

// ---- flattened per-layer epoch barrier ----
// arrive: +1 on this WG's leaf, after all waves' h sc-stores acked at L3.
// (sc-stores bypass L2 straight to L3; vmcnt(0) drain before the add = release.)
__device__ __forceinline__ void layer_arrive(ull* base, int sub) {
  asm volatile("s_waitcnt vmcnt(0)" ::: "memory");
  __syncthreads();
  if (threadIdx.x == 0) AT_ADD(base + 16 + 16 * (sub & 7), 1ull);
}

// min over the 8 leaf counters; 8 independent loads -> ~one L3 RTT per round
__device__ __forceinline__ ull leafmin(const ull* base) {
  ull v[8];
#pragma unroll
  for (int l = 0; l < 8; ++l) v[l] = AT_LD(base + 16 + 16 * l);
  ull m = v[0];
#pragma unroll
  for (int l = 1; l < 8; ++l) m = v[l] < m ? v[l] : m;
  return m;
}

// wait: all leaves of own >= 16*ot and of oth >= 16*xt (skip if <=0), then an
// agent-acquire fence (L2 invalidate) so the cached h loads below see fresh data.
__device__ __forceinline__ void wait2(const ull* own, long long ot, const ull* oth, long long xt) {
  if (threadIdx.x == 0) {
    if (ot > 0) {
      const ull tgt = 16ull * (ull)ot;
      while (leafmin(own) < tgt) __builtin_amdgcn_s_sleep(1);
    }
    if (xt > 0) {
      const ull tgt = 16ull * (ull)xt;
      while (leafmin(oth) < tgt) __builtin_amdgcn_s_sleep(1);
    }
    __builtin_amdgcn_fence(__ATOMIC_ACQUIRE, "agent");
  }
  __syncthreads();
}

// ---- A-fragment load: plain cached 16B load (h coherence via per-step acquire)
__device__ __forceinline__ short8 ldfrag(const char* p) { return *(const short8*)p; }

__device__ __forceinline__ void ringfill(const char* const* aPm, short8 (*af)[4]) {
#pragma unroll
  for (int kt = 0; kt < 8; ++kt)
#pragma unroll
    for (int mt = 0; mt < 4; ++mt) af[kt][mt] = ldfrag(aPm[mt] + kt * 64);
}

__device__ __forceinline__ void kmain(const char* const* aPm, short8 (*af)[4],
                                      const short8 (*bfr)[2], floatx4 (*acc)[2]) {
#pragma unroll
  for (int kt = 0; kt < 16; ++kt) {
#pragma unroll
    for (int mt = 0; mt < 4; ++mt)
#pragma unroll
      for (int nt = 0; nt < 2; ++nt)
        acc[mt][nt] = __builtin_amdgcn_mfma_f32_16x16x32_bf16(
            af[kt & 7][mt], bfr[kt][nt], acc[mt][nt], 0, 0, 0);
    if (kt < 8) {
#pragma unroll
      for (int mt = 0; mt < 4; ++mt)
        af[kt & 7][mt] = ldfrag(aPm[mt] + (kt + 8) * 64);
    }
  }
}

__global__ __launch_bounds__(256, 1) void lstm2_persist(
    const float* __restrict__ xin, const int* __restrict__ lens,
    const float* __restrict__ W0, const float* __restrict__ U0, const float* __restrict__ b0v,
    const float* __restrict__ W1, const float* __restrict__ U1, const float* __restrict__ b1v,
    float* __restrict__ out, ull* __restrict__ ws) {
  extern __shared__ char smem[];
  float* red = (float*)smem;  // [12][2][64][4] f32 = 24KB

  ull* bar0 = ws;           // layer-0 epoch leaves @16+16l (128B apart)
  ull* bar1 = ws + 512;     // layer-1 epoch leaves
  ull* fbar = ws + 1024;    // phase-0 flat full barrier
  unsigned short* hbufs = (unsigned short*)(ws + 2048);  // byte 16384

  const int tid = threadIdx.x;
  const int bid = blockIdx.x;
  const int layer = bid >> 7;
  const int sub = bid & 127;
  const int hc0 = sub * 8;
  const int wave = tid >> 6;
  const int lane = tid & 63;
  const int c16 = lane & 15;
  const int rowgrp = lane >> 4;

  // h0 ring of 4 (layer0 may run ahead), h1 ping-pong of 2. 64x1024 bf16 each.
  unsigned short* h0r[4] = {hbufs, hbufs + 65536, hbufs + 131072, hbufs + 196608};
  unsigned short* h1r[2] = {hbufs + 262144, hbufs + 327680};

  // ---------------- phase 0 ----------------
  const unsigned int gid = (unsigned int)bid * 256u + (unsigned int)tid;
  for (unsigned int i = gid; i < 196608u; i += 65536u) ((unsigned int*)hbufs)[i] = 0u;
  {
    // x (B,T,D) fp32 -> bf16 aliased into d_out at (b*512+t)*4096 bytes.
    const floatx4* xs = (const floatx4*)xin;
    for (unsigned int q = gid; q < 8388608u; q += 65536u) {
      unsigned int d4 = q & 255u;
      unsigned int bt = q >> 8;
      floatx4 v = xs[q];
      ushort4v o;
      o.x = f2bf(v.x); o.y = f2bf(v.y); o.z = f2bf(v.z); o.w = f2bf(v.w);
      *((ushort4v*)((char*)out + (size_t)bt * 4096) + d4) = o;
    }
  }
  // B fragments -> VGPRs (wave w: K in [512w,512w+512); w<2 = W rows, w>=2 = U rows)
  const float* Wm = layer ? W1 : W0;
  const float* Um = layer ? U1 : U0;
  const float* Bsrc = (wave < 2) ? Wm : Um;
  const int kbase = (wave & 1) * 512;
  short8 bf[16][2];
#pragma unroll
  for (int kt = 0; kt < 16; ++kt)
#pragma unroll
    for (int nt = 0; nt < 2; ++nt) {
      const int zc = (nt * 2 + (c16 >> 3)) * 1024 + hc0 + (c16 & 7);
      const float* col = Bsrc + (size_t)(kbase + kt * 32 + rowgrp * 8) * 4096 + zc;
      short8 v;
#pragma unroll
      for (int j = 0; j < 8; ++j) v[j] = (short)f2bf(col[(size_t)j * 4096]);
      bf[kt][nt] = v;
    }
  const float* bv = layer ? b1v : b0v;
  const float bias0 = bv[(c16 >> 3) * 1024 + hc0 + (c16 & 7)];
  const float bias1 = bv[(2 + (c16 >> 3)) * 1024 + hc0 + (c16 & 7)];
  int lens4[4];
#pragma unroll
  for (int r = 0; r < 4; ++r) lens4[r] = lens[wave * 16 + rowgrp * 4 + r];

  fullbar(fbar);

  // ---------------- recurrence ----------------
  float hst[4] = {0.f, 0.f, 0.f, 0.f};
  float cst[4] = {0.f, 0.f, 0.f, 0.f};
  const int col = hc0 + c16;

#pragma unroll 1
  for (int t = 0; t < NTT; ++t) {
    const char* aPm[4];
    short8 af[8][4];
    bool isX;  // this wave's A comes from x (prefetchable) vs h (post-wait only)
    {
      const char* base0;
      size_t pitch;
      if (layer == 0) {
        if (wave < 2) { base0 = (const char*)out + (size_t)t * 4096 + (size_t)wave * 1024;
                        pitch = (size_t)NTT * 4096; isX = true; }
        else          { base0 = (const char*)h0r[(t + 3) & 3] + (size_t)(wave - 2) * 1024;
                        pitch = 2048; isX = false; }
      } else {
        if (wave < 2) { base0 = (const char*)h0r[t & 3] + (size_t)wave * 1024; }
        else          { base0 = (const char*)h1r[(t + 1) & 1] + (size_t)(wave - 2) * 1024; }
        pitch = 2048; isX = false;
      }
      const char* aP = base0 + (size_t)c16 * pitch + (size_t)rowgrp * 16;
#pragma unroll
      for (int mt = 0; mt < 4; ++mt) aPm[mt] = aP + (size_t)mt * 16 * pitch;
    }

    if (isX) ringfill(aPm, af);  // x is static: prefetch before the wait

    if (layer == 0) wait2(bar0, t, bar1, (long long)t - 3);
    else            wait2(bar1, t, bar0, (long long)t + 1);

    floatx4 acc[4][2];
#pragma unroll
    for (int mt = 0; mt < 4; ++mt)
#pragma unroll
      for (int nt = 0; nt < 2; ++nt) { floatx4 z = {0.f, 0.f, 0.f, 0.f}; acc[mt][nt] = z; }

    if (isX) {
      kmain(aPm, af, bf, acc);
    } else {
      ringfill(aPm, af);
      kmain(aPm, af, bf, acc);
    }

    // cross-wave K reduction (wave keeps m-tile == wave)
#pragma unroll
    for (int mt = 0; mt < 4; ++mt)
      if (mt != wave) {
        int slot = mt * 3 + wave - (wave > mt ? 1 : 0);
        *(floatx4*)&red[((slot * 2 + 0) * 64 + lane) * 4] = acc[mt][0];
        *(floatx4*)&red[((slot * 2 + 1) * 64 + lane) * 4] = acc[mt][1];
      }
    __syncthreads();
    floatx4 z0 = acc[wave][0], z1 = acc[wave][1];
#pragma unroll
    for (int q = 0; q < 3; ++q) {
      int slot = wave * 3 + q;
      z0 += *(const floatx4*)&red[((slot * 2 + 0) * 64 + lane) * 4];
      z1 += *(const floatx4*)&red[((slot * 2 + 1) * 64 + lane) * 4];
    }
    z0 += bias0;
    z1 += bias1;

    unsigned short* hW = layer ? h1r[t & 1] : h0r[t & 3];
    float2 f2s[4];

#pragma unroll
    for (int r = 0; r < 4; ++r) {
      float zi = z0[r], zg = z1[r];
      float zf = __shfl_xor(zi, 8);
      float zo = __shfl_xor(zg, 8);
      float h2, hu_f = 0.f;
      unsigned short hu = 0;
      if (c16 < 8) {
        float ig = sigmf(zi), fg = sigmf(zf), gg = tanhfa(zg), og = sigmf(zo);
        float cn = fg * cst[r] + ig * gg;
        float hn = og * tanhfa(cn);
        bool m = t < lens4[r];
        h2 = m ? hn : hst[r];
        float c2 = m ? cn : cst[r];
        hst[r] = h2;
        cst[r] = c2;
        hu = f2bf(h2);
        hu_f = h2;
      }
      // pair adjacent cols -> one u32 coherent (L2-bypass) store
      unsigned int up = __shfl_xor((unsigned int)hu, 1);
      float hp = __shfl_xor(hu_f, 1);
      if (c16 < 8 && !(c16 & 1)) {
        int b = wave * 16 + rowgrp * 4 + r;
        unsigned int w = (unsigned int)hu | (up << 16);
        AT_ST((unsigned int*)(hW + b * 1024 + col), w);
        f2s[r] = make_float2(hu_f, hp);
      }
    }

    if (layer == 0) layer_arrive(bar0, sub);
    else            layer_arrive(bar1, sub);

    // rnnout f32 stores AFTER the arrive: off the vmcnt(0) drain path;
    // they complete during the next step's wait. (Cached stores; flushed at
    // kernel end; this region is never read in-kernel.)
    if (layer && c16 < 8 && !(c16 & 1)) {
#pragma unroll
      for (int r = 0; r < 4; ++r) {
        int b = wave * 16 + rowgrp * 4 + r;
        *(float2*)&out[((size_t)b * 512 + (size_t)t) * 1024 + col] = f2s[r];
      }
    }
  }

  if (layer && c16 < 8) {
#pragma unroll
    for (int r = 0; r < 4; ++r) {
      int b = wave * 16 + rowgrp * 4 + r;
      out[(size_t)33554432 + (size_t)b * 1024 + col] = hst[r];
      out[(size_t)33554432 + 65536 + (size_t)b * 1024 + col] = cst[r];
    }
  }
}

extern "C" void kernel_launch(void* const* d_in, const int* in_sizes, int n_in,
                              void* d_out, int out_size, void* d_ws, size_t ws_size,
                              hipStream_t stream) {
  (void)in_sizes; (void)n_in; (void)out_size; (void)ws_size;
  const float* x  = (const float*)d_in[0];
  const int* lens = (const int*)d_in[1];
  const float* W0 = (const float*)d_in[2];
  const float* U0 = (const float*)d_in[3];
  const float* b0 = (const float*)d_in[4];
  const float* W1 = (const float*)d_in[5];
  const float* U1 = (const float*)d_in[6];
  const float* b1 = (const float*)d_in[7];

  (void)hipFuncSetAttribute((const void*)lstm2_persist,
                            hipFuncAttributeMaxDynamicSharedMemorySize, LDS_TOTAL);
  hipMemsetAsync(d_ws, 0, 16384, stream);  // bar0/bar1/fbar

  lstm2_persist<<<dim3(256), dim3(256), LDS_TOTAL, stream>>>(
      x, lens, W0, U0, b0, W1, U1, b1, (float*)d_out, (ull*)d_ws);
}